// Round 1
// 2302.142 us; speedup vs baseline: 1.2962x; 1.2962x over previous
//
#include <hip/hip_runtime.h>

typedef __bf16 bf16_t;
typedef __bf16 bf16x8 __attribute__((ext_vector_type(8)));
typedef float floatx4 __attribute__((ext_vector_type(4)));

#define GRU_STEPS 120
#define OUTC 31
#define RING 8   // B-prefetch depth; must divide 64 (power of 2)

// ws layout (bytes):
//   blob0 : [0, 524288)          bf16 [8][1024][32]  step-0 weights (x=0)
//   blob1 : [524288, 1048576)    bf16 [8][1024][32]  steady-state weights
//   woutp : [1048576, 1064960)   bf16 [32][256]      W_out padded to 32 rows
//   biasc : [1064960, 1069056)   f32  [1024]         combined gate biases
//   boutp : [1069056, 1069184)   f32  [32]           b_out padded

__global__ void repack_kernel(const float* __restrict__ Wih, const float* __restrict__ Whh,
                              const float* __restrict__ bih, const float* __restrict__ bhh,
                              const float* __restrict__ Wout, const float* __restrict__ bout,
                              bf16_t* __restrict__ blob0, bf16_t* __restrict__ blob1,
                              bf16_t* __restrict__ woutp, float* __restrict__ biasc,
                              float* __restrict__ boutp)
{
    int idx = blockIdx.x * blockDim.x + threadIdx.x;   // 0 .. 1024*256-1
    if (idx >= 1024 * 256) return;
    int n  = idx >> 8;    // blob column (gate output index), 0..1023
    int kk = idx & 255;   // k index, 0..255

    // blob column map: [0,512) r|z combined, [512,768) i_n (W_ih rows 512..767),
    //                  [768,1024) h_n (W_hh rows 512..767)
    float vih = (n < 768) ? Wih[n * 256 + kk] : 0.f;
    float vhh = (n < 512) ? Whh[n * 256 + kk]
                          : ((n >= 768) ? Whh[(n - 256) * 256 + kk] : 0.f);
    float b1 = (n < 512) ? (vih + vhh) : ((n < 768) ? vih : vhh); // t>=1 (x==h)
    float b0 = (n < 512) ? vhh : ((n < 768) ? 0.f : vhh);         // t==0 (x==0)

    int c = kk >> 5, kloc = kk & 31;
    int off = c * (1024 * 32) + n * 32 + kloc;   // [chunk][n][k] k-contiguous
    blob0[off] = (bf16_t)b0;
    blob1[off] = (bf16_t)b1;

    if (n < 32) woutp[n * 256 + kk] = (bf16_t)((n < OUTC) ? Wout[n * 256 + kk] : 0.f);
    if (idx < 1024) {
        float bb = (idx < 512) ? (bih[idx] + bhh[idx])
                               : ((idx < 768) ? bih[idx] : bhh[idx - 256]);
        biasc[idx] = bb;
    }
    if (idx < 32) boutp[idx] = (idx < OUTC) ? bout[idx] : 0.f;
}

__device__ __forceinline__ float sigmoid_f(float x) {
    return __builtin_amdgcn_rcpf(1.f + __expf(-x));
}
__device__ __forceinline__ float tanh_f(float x) {
    // 1 - 2/(1+e^{2x}): exact at +/-inf, monotone, ~1ulp rcp/exp
    return 1.f - 2.f * __builtin_amdgcn_rcpf(1.f + __expf(2.f * x));
}

// One WG (8 waves, 512 thr) per 64 batch rows; runs all 120 steps.
// Wave w owns h columns [w*32, w*32+32). B-operand weights stream from L2
// through an explicit RING-deep register prefetch ring (1 KB coalesced load
// per slot) that is kept in flight ACROSS the per-step barriers: the in-loop
// barriers are raw s_barrier with an lgkmcnt(0)-only drain, so vmcnt never
// drains in the main loop (T4 discipline).
__global__ __launch_bounds__(512, 2)
void gru_main(const float* __restrict__ hidden,
              const bf16_t* __restrict__ blob0, const bf16_t* __restrict__ blob1,
              const bf16_t* __restrict__ woutp, const float* __restrict__ biasc,
              const float* __restrict__ boutp, float* __restrict__ out)
{
    __shared__ bf16_t Abuf[64 * 264];    // h tile, [row][k] bf16, padded
    __shared__ bf16_t WoutB[32 * 264];   // W_out [o][k] bf16, padded

    const int tid = threadIdx.x;
    const int w   = tid >> 6;          // wave 0..7
    const int l16 = tid & 15;          // lane & 15
    const int q   = (tid >> 4) & 3;    // lane quad
    const int rowBase = blockIdx.x * 64;
    const int colBase = w * 32;

    for (int i = tid; i < 32 * 256; i += 512) {
        int n = i >> 8, k = i & 255;
        WoutB[n * 264 + k] = woutp[i];
    }

    float biasv[4][2];
#pragma unroll
    for (int g = 0; g < 4; ++g)
#pragma unroll
        for (int nt = 0; nt < 2; ++nt)
            biasv[g][nt] = biasc[g * 256 + colBase + nt * 16 + l16];
    const float ybias = boutp[(w & 1) * 16 + l16];

    // fp32 h master in registers, mapped exactly like MFMA C-layout:
    // row = mt*16 + q*4 + i, col = colBase + nt*16 + l16
    float h[2][4][4];
#pragma unroll
    for (int nt = 0; nt < 2; ++nt)
#pragma unroll
        for (int mt = 0; mt < 4; ++mt)
#pragma unroll
            for (int i = 0; i < 4; ++i) {
                int row = mt * 16 + q * 4 + i;
                int col = colBase + nt * 16 + l16;
                float v = hidden[(rowBase + row) * 256 + col];
                h[nt][mt][i] = v;
                Abuf[row * 264 + col] = (bf16_t)v;
            }
    __syncthreads();

    // B slot s = c*8 + g*2 + nt. Per-lane byte offset inside a step blob:
    //   c*65536 + g*16384 + nt*1024 + (colBase + l16)*64 + q*16
    // (identical addresses to the old direct loads — layout unchanged, each
    //  wave slot read is one contiguous 1 KB region -> fully coalesced)
    const char* const b0p = (const char*)blob0;
    const char* const b1p = (const char*)blob1;
    const int laneByte = (colBase + l16) * 64 + q * 16;

    bf16x8 ring[RING];

    // prologue: slots 0..RING-1 of step 0 (from blob0)
#pragma unroll
    for (int s = 0; s < RING; ++s) {
        const int c = s >> 3, g = (s >> 1) & 3, nt = s & 1;
        ring[s] = *reinterpret_cast<const bf16x8*>(
            b0p + c * 65536 + g * 16384 + nt * 1024 + laneByte);
    }

    for (int t = 0; t < GRU_STEPS; ++t) {
        const char* const cur = (t == 0) ? b0p : b1p;

        // acc[g][nt][mt]: gate-group g, 16-col subtile nt, 16-row tile mt.
        floatx4 acc[4][2][4];
#pragma unroll
        for (int g = 0; g < 4; ++g)
#pragma unroll
            for (int nt = 0; nt < 2; ++nt) {
                float b = biasv[g][nt];
                floatx4 binit = {b, b, b, b};
#pragma unroll
                for (int mt = 0; mt < 4; ++mt) acc[g][nt][mt] = binit;
            }

#pragma unroll
        for (int c = 0; c < 8; ++c) {      // K chunks of 32
            bf16x8 afr[4];
#pragma unroll
            for (int mt = 0; mt < 4; ++mt)
                afr[mt] = *reinterpret_cast<const bf16x8*>(
                    &Abuf[(mt * 16 + l16) * 264 + c * 32 + q * 8]);
#pragma unroll
            for (int g = 0; g < 4; ++g)
#pragma unroll
                for (int nt = 0; nt < 2; ++nt) {
                    const int s = c * 8 + g * 2 + nt;
                    const bf16x8 bfr = ring[s & (RING - 1)];
#pragma unroll
                    for (int mt = 0; mt < 4; ++mt)
                        acc[g][nt][mt] = __builtin_amdgcn_mfma_f32_16x16x32_bf16(
                            afr[mt], bfr, acc[g][nt][mt], 0, 0, 0);
                    // refill ring with slot s+RING (spills into next step,
                    // which always reads blob1; compile-time branch)
                    const int u = s + RING;
                    if (u < 64) {
                        const int uc = u >> 3, ug = (u >> 1) & 3, un = u & 1;
                        ring[s & (RING - 1)] = *reinterpret_cast<const bf16x8*>(
                            cur + uc * 65536 + ug * 16384 + un * 1024 + laneByte);
                    } else {
                        const int uu = u - 64;
                        const int uc = uu >> 3, ug = (uu >> 1) & 3, un = uu & 1;
                        ring[s & (RING - 1)] = *reinterpret_cast<const bf16x8*>(
                            b1p + uc * 65536 + ug * 16384 + un * 1024 + laneByte);
                    }
                }
        }
        // barrier 1: all A-frag LDS reads done before Abuf rewrite.
        // lgkm-only drain — keep the RING global loads in flight.
        asm volatile("s_waitcnt lgkmcnt(0)" ::: "memory");
        __builtin_amdgcn_s_barrier();

        // wave-local GRU update
#pragma unroll
        for (int nt = 0; nt < 2; ++nt)
#pragma unroll
            for (int mt = 0; mt < 4; ++mt)
#pragma unroll
                for (int i = 0; i < 4; ++i) {
                    float r  = sigmoid_f(acc[0][nt][mt][i]);
                    float z  = sigmoid_f(acc[1][nt][mt][i]);
                    float n  = tanh_f(acc[2][nt][mt][i] + r * acc[3][nt][mt][i]);
                    float hv = n + z * (h[nt][mt][i] - n);
                    h[nt][mt][i] = hv;
                    Abuf[(mt * 16 + q * 4 + i) * 264 + colBase + nt * 16 + l16] =
                        (bf16_t)hv;
                }
        // barrier 2: new h visible to all; again lgkm-only drain.
        asm volatile("s_waitcnt lgkmcnt(0)" ::: "memory");
        __builtin_amdgcn_s_barrier();

        // y = h_new @ W_out^T + b_out ; wave w -> 16x16 tile (mt=w>>1, nt=w&1)
        floatx4 accy = {ybias, ybias, ybias, ybias};
        const int mty = w >> 1, nty = w & 1;
#pragma unroll
        for (int c = 0; c < 8; ++c) {
            bf16x8 a = *reinterpret_cast<const bf16x8*>(
                &Abuf[(mty * 16 + l16) * 264 + c * 32 + q * 8]);
            bf16x8 bw = *reinterpret_cast<const bf16x8*>(
                &WoutB[(nty * 16 + l16) * 264 + c * 32 + q * 8]);
            accy = __builtin_amdgcn_mfma_f32_16x16x32_bf16(a, bw, accy, 0, 0, 0);
        }
        const int ocol = nty * 16 + l16;
        if (ocol < OUTC) {
#pragma unroll
            for (int i = 0; i < 4; ++i) {
                int row = mty * 16 + q * 4 + i;
                out[(size_t)(rowBase + row) * (GRU_STEPS * OUTC) + t * OUTC + ocol] =
                    accy[i];
            }
        }
        // no barrier here: y-phase and next iteration's gate phase both only
        // READ Abuf; the next write is protected by barrier 1 of step t+1.
    }
}

extern "C" void kernel_launch(void* const* d_in, const int* in_sizes, int n_in,
                              void* d_out, int out_size, void* d_ws, size_t ws_size,
                              hipStream_t stream)
{
    const float* hidden = (const float*)d_in[0];
    const float* Wih    = (const float*)d_in[1];
    const float* Whh    = (const float*)d_in[2];
    const float* bih    = (const float*)d_in[3];
    const float* bhh    = (const float*)d_in[4];
    const float* Wout   = (const float*)d_in[5];
    const float* bout   = (const float*)d_in[6];
    float* out = (float*)d_out;

    char* ws = (char*)d_ws;
    bf16_t* blob0 = (bf16_t*)(ws);
    bf16_t* blob1 = (bf16_t*)(ws + 524288);
    bf16_t* woutp = (bf16_t*)(ws + 1048576);
    float*  biasc = (float*)(ws + 1064960);
    float*  boutp = (float*)(ws + 1069056);

    repack_kernel<<<1024, 256, 0, stream>>>(Wih, Whh, bih, bhh, Wout, bout,
                                            blob0, blob1, woutp, biasc, boutp);
    gru_main<<<256, 512, 0, stream>>>(hidden, blob0, blob1, woutp, biasc, boutp, out);
}